// Round 7
// baseline (329.061 us; speedup 1.0000x reference)
//
#include <hip/hip_runtime.h>
#include <cstdint>
#include <cstddef>

// ---------------- problem constants (fixed by setup_inputs) ----------------
#define B_  4
#define T_  2048
#define D_  512
#define NH_ 8
#define HD_ 64
#define FF_ 2048
#define M_  (B_*T_)   // 8192 token rows

typedef unsigned short u16;
typedef __attribute__((ext_vector_type(8))) unsigned short u16x8;
typedef __attribute__((ext_vector_type(8))) __bf16         bf16x8;
typedef __attribute__((ext_vector_type(4))) float          f32x4;

__device__ __forceinline__ u16 f2bf(float f) {            // RNE f32 -> bf16
  unsigned u = __float_as_uint(f);
  u += 0x7FFF + ((u >> 16) & 1);
  return (u16)(u >> 16);
}
__device__ __forceinline__ float bf2f(u16 h) {
  return __uint_as_float((unsigned)h << 16);
}

__device__ __forceinline__ f32x4 mfma_bf16(u16x8 a, u16x8 b, f32x4 c) {
  return __builtin_amdgcn_mfma_f32_16x16x32_bf16(
      __builtin_bit_cast(bf16x8, a), __builtin_bit_cast(bf16x8, b), c, 0, 0, 0);
}

// async global->LDS, 16B per lane; LDS dest = wave-uniform base + lane*16
__device__ __forceinline__ void async16(const void* g, void* l) {
  __builtin_amdgcn_global_load_lds(
      (const __attribute__((address_space(1))) unsigned int*)g,
      (__attribute__((address_space(3))) unsigned int*)l, 16, 0, 0);
}

// Branchless GELU via A&S 7.1.26 erf (|err| <= 1.5e-7).
__device__ __forceinline__ float gelu_f(float v) {
  float ax = fabsf(v) * 0.70710678118f;
  float t = 1.0f / (1.0f + 0.3275911f * ax);
  float p = ((((1.061405429f * t - 1.453152027f) * t + 1.421413741f) * t
              - 0.284496736f) * t + 0.254829592f) * t;
  float e = __expf(-ax * ax);
  float er = 1.0f - p * e;
  float s = (v >= 0.0f) ? er : -er;
  return 0.5f * v * (1.0f + s);
}

// ---- fused prep: 4 weight transposes (norm weights FOLDED into wqkv/w1)
// + x->bf16 + per-row inv-rms, in ONE launch.
__global__ __launch_bounds__(256) void prep_kernel(
    const float* __restrict__ i0, u16* __restrict__ o0,   // wqkv 512x1536
    const float* __restrict__ i1, u16* __restrict__ o1,   // wout 512x512
    const float* __restrict__ i2, u16* __restrict__ o2,   // w1   512x2048
    const float* __restrict__ i3, u16* __restrict__ o3,   // w2   2048x512
    const float* __restrict__ x, const float* __restrict__ n1w,
    const float* __restrict__ n2w,
    float* __restrict__ inv, u16* __restrict__ xbf) {
  __shared__ float tile[32][33];
  const int bid = blockIdx.x, tid = threadIdx.x;
  if (bid < 3072) {
    const float* in; u16* out; const float* sc; int R, C, gx, lb;
    if (bid < 768)       { in = i0; out = o0; R = 512;  C = 1536; gx = 48; lb = bid;        sc = n1w; }
    else if (bid < 1024) { in = i1; out = o1; R = 512;  C = 512;  gx = 16; lb = bid - 768;  sc = nullptr; }
    else if (bid < 2048) { in = i2; out = o2; R = 512;  C = 2048; gx = 64; lb = bid - 1024; sc = n2w; }
    else                 { in = i3; out = o3; R = 2048; C = 512;  gx = 16; lb = bid - 2048; sc = nullptr; }
    int c0 = (lb % gx) * 32, r0 = (lb / gx) * 32;
    int tx = tid & 31, ty = tid >> 5;  // 32x8
#pragma unroll
    for (int i = 0; i < 4; i++)
      tile[ty + i * 8][tx] = in[(size_t)(r0 + ty + i * 8) * C + c0 + tx];
    __syncthreads();
    float s = sc ? sc[r0 + tx] : 1.0f;   // k-index = r0+tx after transpose
#pragma unroll
    for (int i = 0; i < 4; i++)
      out[(size_t)(c0 + ty + i * 8) * R + r0 + tx] = f2bf(tile[tx][ty + i * 8] * s);
  } else {
    int row  = (bid - 3072) * 4 + (tid >> 6);
    int lane = tid & 63;
    const float* xr = x + (size_t)row * D_ + lane * 8;
    float v[8];
    *(float4*)(v)     = *(const float4*)xr;
    *(float4*)(v + 4) = *(const float4*)(xr + 4);
    u16 rw[8];
#pragma unroll
    for (int e = 0; e < 8; e++) rw[e] = f2bf(v[e]);
    *(uint4*)(xbf + (size_t)row * D_ + lane * 8) = *(uint4*)rw;
    float ss = 0.f;
#pragma unroll
    for (int e = 0; e < 8; e++) ss += v[e] * v[e];
#pragma unroll
    for (int m = 1; m < 64; m <<= 1) ss += __shfl_xor(ss, m, 64);
    if (lane == 0) inv[row] = rsqrtf(ss * (1.0f / D_) + 1e-6f);
  }
}

// ---- 2-phase bf16 MFMA GEMM with COUNTED vmcnt (T4). REP: in-kernel repeat
// of the ENTIRE computation (idempotent re-store) -- MEASUREMENT AID so the
// kernel's duration exceeds the 44us harness fills and surfaces in the
// rocprof top-5 with full counters. dur/REP ~= per-pass time (warm caveat).
template <int BM, int BN, bool HAS_BIAS, int RES_MODE, bool DO_GELU,
          bool STORE_BF16, int SCALE_MODE, bool EMIT_SS, int REP>
__global__ __launch_bounds__(256) void gemm_kernel(
    const u16* __restrict__ A, const u16* __restrict__ Bt, void* __restrict__ Cv,
    const float* __restrict__ bias, const void* __restrict__ resv,
    const float* __restrict__ rowscale, float* __restrict__ ssout,
    int M, int N, int K) {
  constexpr int ACH = BM / 32;
  constexpr int BCH = BN / 32;
  constexpr int NLD = ACH + BCH;            // loads per stage per thread
  constexpr int WM  = BM / 2, WN = BN / 2;
  constexpr int MI  = WM / 16, NJ = WN / 16;
  constexpr int EW  = BN + 4;
  constexpr int STG = (BM + BN) * 128;
  constexpr int EPB = 32 * EW * 4;
  constexpr int SMB = (2 * STG > EPB) ? 2 * STG : EPB;
  static_assert(NLD == 6 || NLD == 8, "vmcnt literal covers 6 or 8");
  __shared__ __align__(16) char smem[SMB];
  const int tid = threadIdx.x;
  const int lane = tid & 63, w = tid >> 6;
  const int quad = lane >> 4, m16 = lane & 15;
  const int wm = w & 1, wn = w >> 1;

  const int nbx  = N / BN;
  const int wg   = blockIdx.x;
  const int xcd  = wg & 7, slot = wg >> 3;
  const int mper = (M / BM) >> 3;
  const int mloc = slot / nbx;
  const int nxp  = slot - mloc * nbx;
  const int m0 = (xcd * mper + mloc) * BM, n0 = nxp * BN;

  f32x4 acc[MI][NJ];

  const int srow = tid >> 3;
  const int scol = (((tid & 7) ^ (srow & 7))) * 8;
  const u16* Ag = A  + (size_t)(m0 + srow) * K + scol;
  const u16* Bg = Bt + (size_t)(n0 + srow) * K + scol;

  auto stage = [&](int buf, int kt) {
    char* base = smem + buf * STG;
#pragma unroll
    for (int c = 0; c < ACH; c++)
      async16(Ag + (size_t)c * 32 * K + kt, base + c * 4096 + tid * 16);
#pragma unroll
    for (int c = 0; c < BCH; c++)
      async16(Bg + (size_t)c * 32 * K + kt, base + BM * 128 + c * 4096 + tid * 16);
  };
  auto compute = [&](int buf) {
    const u16* lA = (const u16*)(smem + buf * STG);
    const u16* lB = (const u16*)(smem + buf * STG + BM * 128);
#pragma unroll
    for (int kk = 0; kk < 2; kk++) {
      const int sl = ((kk * 4 + quad) ^ (m16 & 7)) * 8;
      const u16* pa = lA + (wm * WM + m16) * 64 + sl;
      const u16* pb = lB + (wn * WN + m16) * 64 + sl;
      u16x8 af[MI], bfr[NJ];
#pragma unroll
      for (int i = 0; i < MI; i++) af[i] = *(const u16x8*)(pa + i * 1024);
#pragma unroll
      for (int j = 0; j < NJ; j++) bfr[j] = *(const u16x8*)(pb + j * 1024);
#pragma unroll
      for (int i = 0; i < MI; i++)
#pragma unroll
        for (int j = 0; j < NJ; j++)
          acc[i][j] = mfma_bf16(af[i], bfr[j], acc[i][j]);
    }
  };

  const int nk = K >> 6;
  for (int rep = 0; rep < REP; ++rep) {
    __syncthreads();                              // protect smem across reps
#pragma unroll
    for (int i = 0; i < MI; i++)
#pragma unroll
      for (int j = 0; j < NJ; j++) acc[i][j] = (f32x4){0.f, 0.f, 0.f, 0.f};

    stage(0, 0);
    for (int t = 0; t < nk; t++) {
      if (t + 1 < nk) {
        stage((t + 1) & 1, (t + 1) << 6);         // NLD loads, stay in flight
        if constexpr (NLD == 6)
          asm volatile("s_waitcnt vmcnt(6)" ::: "memory");
        else
          asm volatile("s_waitcnt vmcnt(8)" ::: "memory");
      } else {
        asm volatile("s_waitcnt vmcnt(0)" ::: "memory");  // final drain
      }
      __builtin_amdgcn_s_barrier();               // globalize stage(t)
      compute(t & 1);
      __builtin_amdgcn_s_barrier();               // reads done before overwrite
    }

    float* eps = (float*)smem;
    constexpr int REPS = (32 * BN) / (256 * 8);
    float bv[REPS > 0 ? REPS : 1][8];
    if (HAS_BIAS) {
#pragma unroll
      for (int r2 = 0; r2 < REPS; r2++) {
        const int col = (BN == 128) ? ((tid & 15) * 8) : ((tid & 7) * 8);
        *(float4*)(bv[r2])     = *(const float4*)(bias + n0 + col);
        *(float4*)(bv[r2] + 4) = *(const float4*)(bias + n0 + col + 4);
      }
    }
#pragma unroll
    for (int i = 0; i < MI; i++) {
      __syncthreads();
#pragma unroll
      for (int j = 0; j < NJ; j++)
#pragma unroll
        for (int r = 0; r < 4; r++)
          eps[(wm * 16 + quad * 4 + r) * EW + wn * WN + j * 16 + m16] =
              acc[i][j][r];
      __syncthreads();
#pragma unroll
      for (int r2 = 0; r2 < REPS; r2++) {
        const int lr  = (BN == 128) ? (r2 * 16 + (tid >> 4)) : (tid >> 3);
        const int col = (BN == 128) ? ((tid & 15) * 8) : ((tid & 7) * 8);
        const int rg  = m0 + (lr >> 4) * WM + i * 16 + (lr & 15);
        float v[8];
        *(float4*)(v)     = *(const float4*)(eps + lr * EW + col);
        *(float4*)(v + 4) = *(const float4*)(eps + lr * EW + col + 4);
        if (SCALE_MODE != 0) {
          float rs;
          if (SCALE_MODE == 1)      rs = rowscale[rg];
          else if (SCALE_MODE == 2) rs = rsqrtf(rowscale[rg] * (1.0f / D_) + 1e-6f);
          else {
            float s4 = rowscale[rg] + rowscale[M_ + rg] +
                       rowscale[2 * M_ + rg] + rowscale[3 * M_ + rg];
            rs = rsqrtf(s4 * (1.0f / D_) + 1e-6f);
          }
#pragma unroll
          for (int e = 0; e < 8; e++) v[e] *= rs;
        }
        if (HAS_BIAS) {
#pragma unroll
          for (int e = 0; e < 8; e++) v[e] += bv[r2][e];
        }
        if (DO_GELU) {
#pragma unroll
          for (int e = 0; e < 8; e++) v[e] = gelu_f(v[e]);
        }
        const size_t idx = (size_t)rg * N + n0 + col;
        if (RES_MODE == 1) {
          float4 r0 = *(const float4*)((const float*)resv + idx);
          float4 r1 = *(const float4*)((const float*)resv + idx + 4);
          v[0] += r0.x; v[1] += r0.y; v[2] += r0.z; v[3] += r0.w;
          v[4] += r1.x; v[5] += r1.y; v[6] += r1.z; v[7] += r1.w;
        } else if (RES_MODE == 2) {
          u16x8 rr = *(const u16x8*)((const u16*)resv + idx);
#pragma unroll
          for (int e = 0; e < 8; e++) v[e] += bf2f(rr[e]);
        }
        if (EMIT_SS) {   // per-row partial sumsq, plain store (idempotent)
          float ps = 0.f;
#pragma unroll
          for (int e = 0; e < 8; e++) ps += v[e] * v[e];
          ps += __shfl_xor(ps, 1, 64);
          ps += __shfl_xor(ps, 2, 64);
          ps += __shfl_xor(ps, 4, 64);
          ps += __shfl_xor(ps, 8, 64);
          if ((tid & 15) == 0) ssout[(size_t)nxp * M + rg] = ps;
        }
        if (STORE_BF16) {
          u16 o[8];
#pragma unroll
          for (int e = 0; e < 8; e++) o[e] = f2bf(v[e]);
          *(uint4*)((u16*)Cv + idx) = *(uint4*)o;
        } else {
          *(float4*)((float*)Cv + idx)     = *(float4*)(v);
          *(float4*)((float*)Cv + idx + 4) = *(float4*)(v + 4);
        }
      }
    }
  }
}

// ---- banded attention, MFMA flash-style. REP = measurement repeat (pure).
#define VP_ 216
template <int REP>
__global__ __launch_bounds__(256) void attn_kernel(const u16* __restrict__ qkv,
                                                   u16* __restrict__ out) {
  __shared__ __align__(16) char smem[26624 + 64 * VP_ * 2];
  u16* Ks = (u16*)smem;               // [208][64] keys, swizzled (26624 B)
  u16* Vt = (u16*)(smem + 26624);     // [64][216] V transposed (27648 B)
  const int tid = threadIdx.x, lane = tid & 63, w = tid >> 6;
  const int quad = lane >> 4, m16 = lane & 15;
  const int qc = ((blockIdx.x & 7) << 2) | (blockIdx.x >> 3);  // XCD swizzle
  const int q0 = qc * 64, h = blockIdx.y, b = blockIdx.z;
  const int kstart = q0 - 64;         // 208-key staging window
  const u16* base = qkv + (size_t)b * T_ * 1536;

  for (int rep = 0; rep < REP; ++rep) {
    __syncthreads();                  // protect smem across reps
#pragma unroll
    for (int r6 = 0; r6 < 6; r6++) {
      int c = r6 * 256 + tid;
      int row = c >> 3;
      int j = kstart + row;
      j = j < 0 ? 0 : (j > T_ - 1 ? T_ - 1 : j);
      int srcch = ((c & 7) ^ (row & 7)) * 8;
      async16(base + (size_t)j * 1536 + 512 + h * 64 + srcch, smem + c * 16);
    }
    if (tid < 128) {
      int c = 1536 + tid;
      int row = c >> 3;
      int j = kstart + row;
      j = j < 0 ? 0 : (j > T_ - 1 ? T_ - 1 : j);
      int srcch = ((c & 7) ^ (row & 7)) * 8;
      async16(base + (size_t)j * 1536 + 512 + h * 64 + srcch, smem + c * 16);
    }
    for (int c = tid; c < 1664; c += 256) {
      int row = c >> 3, cc = (c & 7) * 8;
      int j = kstart + row;
      j = j < 0 ? 0 : (j > T_ - 1 ? T_ - 1 : j);
      uint4 u = *(const uint4*)(base + (size_t)j * 1536 + 1024 + h * 64 + cc);
      u16 tmp[8];
      *(uint4*)tmp = u;
#pragma unroll
      for (int i = 0; i < 8; i++) Vt[(cc + i) * VP_ + row] = tmp[i];
    }
    const int qw = q0 + w * 16;
    const u16* qb = base + (size_t)(qw + m16) * 1536 + h * 64 + quad * 8;
    u16x8 a0 = *(const u16x8*)qb;
    u16x8 a1 = *(const u16x8*)(qb + 32);
    __syncthreads();

    float s[10][4];
#pragma unroll
    for (int t = 0; t < 10; t++) {
      int kt = (w + t) * 16;
      int kr = kt + m16, sw = kr & 7;
      u16x8 kb0 = *(const u16x8*)(Ks + kr * 64 + ((quad ^ sw) * 8));
      u16x8 kb1 = *(const u16x8*)(Ks + kr * 64 + (((4 + quad) ^ sw) * 8));
      f32x4 acc = {0.f, 0.f, 0.f, 0.f};
      acc = mfma_bf16(a0, kb0, acc);
      acc = mfma_bf16(a1, kb1, acc);
      int jab = kstart + kt + m16;
#pragma unroll
      for (int r = 0; r < 4; r++) {
        int q = qw + quad * 4 + r;
        int d = q - jab;
        bool valid = (jab >= 0) && (jab < T_) && (d <= 64) && (d >= -64);
        s[t][r] = valid ? acc[r] * 0.125f : -1e30f;
      }
    }
    float mx[4], sm[4];
#pragma unroll
    for (int r = 0; r < 4; r++) mx[r] = -1e30f;
#pragma unroll
    for (int t = 0; t < 10; t++)
#pragma unroll
      for (int r = 0; r < 4; r++) mx[r] = fmaxf(mx[r], s[t][r]);
#pragma unroll
    for (int r = 0; r < 4; r++) {
#pragma unroll
      for (int msk = 1; msk < 16; msk <<= 1)
        mx[r] = fmaxf(mx[r], __shfl_xor(mx[r], msk, 64));
      sm[r] = 0.f;
    }
#pragma unroll
    for (int t = 0; t < 10; t++)
#pragma unroll
      for (int r = 0; r < 4; r++) {
        float e = __expf(s[t][r] - mx[r]);
        s[t][r] = e; sm[r] += e;
      }
#pragma unroll
    for (int r = 0; r < 4; r++) {
#pragma unroll
      for (int msk = 1; msk < 16; msk <<= 1) sm[r] += __shfl_xor(sm[r], msk, 64);
      sm[r] = 1.0f / sm[r];
    }
    __syncthreads();
    u16* Ps = (u16*)smem + w * 2688;     // alias Ks region: per-wave [16][168]
#pragma unroll
    for (int t = 0; t < 10; t++)
#pragma unroll
      for (int r = 0; r < 4; r++)
        Ps[(quad * 4 + r) * 168 + t * 16 + m16] = f2bf(s[t][r] * sm[r]);
    __syncthreads();

    f32x4 o[4];
#pragma unroll
    for (int dt = 0; dt < 4; dt++) o[dt] = (f32x4){0.f, 0.f, 0.f, 0.f};
#pragma unroll
    for (int c5 = 0; c5 < 5; c5++) {
      u16x8 pa = *(const u16x8*)(Ps + m16 * 168 + c5 * 32 + quad * 8);
#pragma unroll
      for (int dt = 0; dt < 4; dt++) {
        u16x8 vb = *(const u16x8*)(Vt + (dt * 16 + m16) * VP_ + w * 16 + c5 * 32 + quad * 8);
        o[dt] = mfma_bf16(pa, vb, o[dt]);
      }
    }
#pragma unroll
    for (int dt = 0; dt < 4; dt++)
#pragma unroll
      for (int r = 0; r < 4; r++)
        out[(size_t)(b * T_ + qw + quad * 4 + r) * D_ + h * HD_ + dt * 16 + m16] =
            f2bf(o[dt][r]);
  }
}

// ---------------------------------------------------------------------------
extern "C" void kernel_launch(void* const* d_in, const int* in_sizes, int n_in,
                              void* d_out, int out_size, void* d_ws, size_t ws_size,
                              hipStream_t stream) {
  (void)in_sizes; (void)n_in; (void)out_size; (void)ws_size;
  const float* x     = (const float*)d_in[0];
  const float* n1w   = (const float*)d_in[1];
  const float* n2w   = (const float*)d_in[2];
  const float* w_qkv = (const float*)d_in[3];
  const float* w_out = (const float*)d_in[4];
  const float* b_out = (const float*)d_in[5];
  const float* w1    = (const float*)d_in[6];
  const float* b1    = (const float*)d_in[7];
  const float* w2    = (const float*)d_in[8];
  const float* b2    = (const float*)d_in[9];
  float* out = (float*)d_out;
  char* ws = (char*)d_ws;

  // workspace layout (hbuf aliases dead qkv+attno)
  u16* wqkvT  = (u16*)(ws + 0);          // [1536][512]  1.5 MB (n1w folded)
  u16* woutT  = (u16*)(ws + 1572864);    // [512][512]   0.5 MB
  u16* w1T    = (u16*)(ws + 2097152);    // [2048][512]  2 MB  (n2w folded)
  u16* w2T    = (u16*)(ws + 4194304);    // [512][2048]  2 MB
  float* inv  = (float*)(ws + 6291456);  // [8192] f32 inv-rms of x
  float* sums4= (float*)(ws + 6324224);  // [4][8192] f32 partial sumsq of x1
  u16* qkv    = (u16*)(ws + 14680064);   // [8192][1536] 24 MB
  u16* attno  = (u16*)(ws + 39845888);   // [8192][512]  8 MB
  u16* x1     = (u16*)(ws + 48234496);   // [8192][512]  8 MB bf16
  u16* xbf    = (u16*)(ws + 56623104);   // [8192][512]  8 MB bf16 (raw x)
  u16* hbuf   = qkv;                     // [8192][2048] 32 MB (over qkv+attno)

  // fused: weight transposes (+norm-w fold) + x->bf16 + inv-rms
  prep_kernel<<<5120, 256, 0, stream>>>(
      w_qkv, wqkvT, w_out, woutT, w1, w1T, w2, w2T, x, n1w, n2w, inv, xbf);

  // ===== MEASUREMENT ROUND: REP-inflated launches so each hot kernel =====
  // ===== exceeds the 44us fills and surfaces in top-5 with counters. =====

  // qkv = (x @ [n1w*wqkv]) * inv[row]    REP=2
  gemm_kernel<64, 128, false, 0, false, true, 1, false, 2>
      <<<dim3(12 * 128), 256, 0, stream>>>(
      xbf, wqkvT, (void*)qkv, nullptr, nullptr, inv, nullptr, M_, 3 * D_, D_);
  // attention  REP=3
  attn_kernel<3><<<dim3(32, 8, 4), 256, 0, stream>>>(qkv, attno);
  // x1 = attno @ w_out + b_out + xbf (+sumsq partials)   REP=4
  gemm_kernel<64, 128, true, 2, false, true, 0, true, 4>
      <<<dim3(4 * 128), 256, 0, stream>>>(
      attno, woutT, (void*)x1, b_out, xbf, nullptr, sums4, M_, D_, D_);
  // hbuf = gelu((x1 @ [n2w*w1]) * rsqrt(sum4/512+eps) + b1)   REP=2
  gemm_kernel<128, 128, true, 0, true, true, 3, false, 2>
      <<<dim3(16 * 64), 256, 0, stream>>>(
      x1, w1T, (void*)hbuf, b1, nullptr, sums4, nullptr, M_, FF_, D_);
  // out = hbuf @ w2 + b2 + x1   REP=2
  gemm_kernel<128, 128, true, 2, false, false, 0, false, 2>
      <<<dim3(4 * 64), 256, 0, stream>>>(
      hbuf, w2T, (void*)out, b2, x1, nullptr, nullptr, M_, D_, FF_);
}

// Round 8
// 196.193 us; speedup vs baseline: 1.6772x; 1.6772x over previous
//
#include <hip/hip_runtime.h>
#include <cstdint>
#include <cstddef>

// ---------------- problem constants (fixed by setup_inputs) ----------------
#define B_  4
#define T_  2048
#define D_  512
#define NH_ 8
#define HD_ 64
#define FF_ 2048
#define M_  (B_*T_)   // 8192 token rows

typedef unsigned short u16;
typedef __attribute__((ext_vector_type(8))) unsigned short u16x8;
typedef __attribute__((ext_vector_type(8))) __bf16         bf16x8;
typedef __attribute__((ext_vector_type(4))) float          f32x4;

__device__ __forceinline__ u16 f2bf(float f) {            // RNE f32 -> bf16
  unsigned u = __float_as_uint(f);
  u += 0x7FFF + ((u >> 16) & 1);
  return (u16)(u >> 16);
}
__device__ __forceinline__ float bf2f(u16 h) {
  return __uint_as_float((unsigned)h << 16);
}

__device__ __forceinline__ f32x4 mfma_bf16(u16x8 a, u16x8 b, f32x4 c) {
  return __builtin_amdgcn_mfma_f32_16x16x32_bf16(
      __builtin_bit_cast(bf16x8, a), __builtin_bit_cast(bf16x8, b), c, 0, 0, 0);
}

// async global->LDS, 16B per lane; LDS dest = wave-uniform base + lane*16
__device__ __forceinline__ void async16(const void* g, void* l) {
  __builtin_amdgcn_global_load_lds(
      (const __attribute__((address_space(1))) unsigned int*)g,
      (__attribute__((address_space(3))) unsigned int*)l, 16, 0, 0);
}

// Branchless GELU via A&S 7.1.26 erf (|err| <= 1.5e-7).
// v_rcp_f32 (1 ulp) instead of IEEE divide (~8-inst sequence w/o fast-math).
__device__ __forceinline__ float gelu_f(float v) {
  float ax = fabsf(v) * 0.70710678118f;
  float t = __builtin_amdgcn_rcpf(1.0f + 0.3275911f * ax);
  float p = ((((1.061405429f * t - 1.453152027f) * t + 1.421413741f) * t
              - 0.284496736f) * t + 0.254829592f) * t;
  float e = __expf(-ax * ax);
  float er = 1.0f - p * e;
  float s = (v >= 0.0f) ? er : -er;
  return 0.5f * v * (1.0f + s);
}

// ---- fused prep: 4 weight transposes (norm weights FOLDED into wqkv/w1)
// + x->bf16 + per-row inv-rms, in ONE launch.
__global__ __launch_bounds__(256) void prep_kernel(
    const float* __restrict__ i0, u16* __restrict__ o0,   // wqkv 512x1536
    const float* __restrict__ i1, u16* __restrict__ o1,   // wout 512x512
    const float* __restrict__ i2, u16* __restrict__ o2,   // w1   512x2048
    const float* __restrict__ i3, u16* __restrict__ o3,   // w2   2048x512
    const float* __restrict__ x, const float* __restrict__ n1w,
    const float* __restrict__ n2w,
    float* __restrict__ inv, u16* __restrict__ xbf) {
  __shared__ float tile[32][33];
  const int bid = blockIdx.x, tid = threadIdx.x;
  if (bid < 3072) {
    const float* in; u16* out; const float* sc; int R, C, gx, lb;
    if (bid < 768)       { in = i0; out = o0; R = 512;  C = 1536; gx = 48; lb = bid;        sc = n1w; }
    else if (bid < 1024) { in = i1; out = o1; R = 512;  C = 512;  gx = 16; lb = bid - 768;  sc = nullptr; }
    else if (bid < 2048) { in = i2; out = o2; R = 512;  C = 2048; gx = 64; lb = bid - 1024; sc = n2w; }
    else                 { in = i3; out = o3; R = 2048; C = 512;  gx = 16; lb = bid - 2048; sc = nullptr; }
    int c0 = (lb % gx) * 32, r0 = (lb / gx) * 32;
    int tx = tid & 31, ty = tid >> 5;  // 32x8
#pragma unroll
    for (int i = 0; i < 4; i++)
      tile[ty + i * 8][tx] = in[(size_t)(r0 + ty + i * 8) * C + c0 + tx];
    __syncthreads();
    float s = sc ? sc[r0 + tx] : 1.0f;   // k-index = r0+tx after transpose
#pragma unroll
    for (int i = 0; i < 4; i++)
      out[(size_t)(c0 + ty + i * 8) * R + r0 + tx] = f2bf(tile[tx][ty + i * 8] * s);
  } else {
    int row  = (bid - 3072) * 4 + (tid >> 6);
    int lane = tid & 63;
    const float* xr = x + (size_t)row * D_ + lane * 8;
    float v[8];
    *(float4*)(v)     = *(const float4*)xr;
    *(float4*)(v + 4) = *(const float4*)(xr + 4);
    u16 rw[8];
#pragma unroll
    for (int e = 0; e < 8; e++) rw[e] = f2bf(v[e]);
    *(uint4*)(xbf + (size_t)row * D_ + lane * 8) = *(uint4*)rw;
    float ss = 0.f;
#pragma unroll
    for (int e = 0; e < 8; e++) ss += v[e] * v[e];
#pragma unroll
    for (int m = 1; m < 64; m <<= 1) ss += __shfl_xor(ss, m, 64);
    if (lane == 0) inv[row] = rsqrtf(ss * (1.0f / D_) + 1e-6f);
  }
}

// ---- 2-phase bf16 MFMA GEMM (64x64 / 64x128 / 128x128) with COUNTED vmcnt:
// per K-step: issue stage(t+1) -> vmcnt(NLD) (stage(t) certified per-wave;
// stage(t+1)'s NLD loads stay in flight through compute) -> barrier
// (globalize) -> compute(t) -> trailing barrier (overwrite safety).
// Tile choice = occupancy lever: 64x64 -> 32KB LDS -> 5 blocks/CU (20 waves),
// 64x128 -> 48KB -> 3/CU, 128x128 -> 64KB -> 2/CU. ffn1 measured 50% dead
// stall at 2/CU (r7: MfmaUtil 18.7, VALUBusy 49) -> raise TLP.
// RES_MODE: 0 none, 1 f32, 2 bf16.
// SCALE_MODE (pre-bias): 0 none, 1 v*=rowscale[rg],
//   2 v*=rsqrt(rowscale[rg]/512+eps),
//   3 v*=rsqrt(sum4(rowscale[p*M_+rg])/512+eps)  (fused rmsnorm2).
// EMIT_SS: per-row partial sumsq of FINAL value -> ssout[nxp*M+rg] (no atomics).
// 1D grid, XCD working-set swizzle (wg&7 = xcd; contiguous m-chunk per XCD).
template <int BM, int BN, bool HAS_BIAS, int RES_MODE, bool DO_GELU,
          bool STORE_BF16, int SCALE_MODE, bool EMIT_SS>
__global__ __launch_bounds__(256) void gemm_kernel(
    const u16* __restrict__ A, const u16* __restrict__ Bt, void* __restrict__ Cv,
    const float* __restrict__ bias, const void* __restrict__ resv,
    const float* __restrict__ rowscale, float* __restrict__ ssout,
    int M, int N, int K) {
  constexpr int ACH = BM / 32;
  constexpr int BCH = BN / 32;
  constexpr int NLD = ACH + BCH;            // loads per stage per thread
  constexpr int WM  = BM / 2, WN = BN / 2;
  constexpr int MI  = WM / 16, NJ = WN / 16;
  constexpr int EW  = BN + 4;
  constexpr int STG = (BM + BN) * 128;
  constexpr int EPB = 32 * EW * 4;
  constexpr int SMB = (2 * STG > EPB) ? 2 * STG : EPB;
  static_assert(NLD == 4 || NLD == 6 || NLD == 8, "vmcnt literal coverage");
  __shared__ __align__(16) char smem[SMB];
  const int tid = threadIdx.x;
  const int lane = tid & 63, w = tid >> 6;
  const int quad = lane >> 4, m16 = lane & 15;
  const int wm = w & 1, wn = w >> 1;

  const int nbx  = N / BN;
  const int wg   = blockIdx.x;
  const int xcd  = wg & 7, slot = wg >> 3;
  const int mper = (M / BM) >> 3;
  const int mloc = slot / nbx;
  const int nxp  = slot - mloc * nbx;
  const int m0 = (xcd * mper + mloc) * BM, n0 = nxp * BN;

  f32x4 acc[MI][NJ];
#pragma unroll
  for (int i = 0; i < MI; i++)
#pragma unroll
    for (int j = 0; j < NJ; j++) acc[i][j] = (f32x4){0.f, 0.f, 0.f, 0.f};

  const int srow = tid >> 3;
  const int scol = (((tid & 7) ^ (srow & 7))) * 8;
  const u16* Ag = A  + (size_t)(m0 + srow) * K + scol;
  const u16* Bg = Bt + (size_t)(n0 + srow) * K + scol;

  auto stage = [&](int buf, int kt) {
    char* base = smem + buf * STG;
#pragma unroll
    for (int c = 0; c < ACH; c++)
      async16(Ag + (size_t)c * 32 * K + kt, base + c * 4096 + tid * 16);
#pragma unroll
    for (int c = 0; c < BCH; c++)
      async16(Bg + (size_t)c * 32 * K + kt, base + BM * 128 + c * 4096 + tid * 16);
  };
  auto compute = [&](int buf) {
    const u16* lA = (const u16*)(smem + buf * STG);
    const u16* lB = (const u16*)(smem + buf * STG + BM * 128);
#pragma unroll
    for (int kk = 0; kk < 2; kk++) {
      const int sl = ((kk * 4 + quad) ^ (m16 & 7)) * 8;
      const u16* pa = lA + (wm * WM + m16) * 64 + sl;
      const u16* pb = lB + (wn * WN + m16) * 64 + sl;
      u16x8 af[MI], bfr[NJ];
#pragma unroll
      for (int i = 0; i < MI; i++) af[i] = *(const u16x8*)(pa + i * 1024);
#pragma unroll
      for (int j = 0; j < NJ; j++) bfr[j] = *(const u16x8*)(pb + j * 1024);
#pragma unroll
      for (int i = 0; i < MI; i++)
#pragma unroll
        for (int j = 0; j < NJ; j++)
          acc[i][j] = mfma_bf16(af[i], bfr[j], acc[i][j]);
    }
  };

  const int nk = K >> 6;
  stage(0, 0);
  for (int t = 0; t < nk; t++) {
    if (t + 1 < nk) {
      stage((t + 1) & 1, (t + 1) << 6);           // NLD loads, stay in flight
      if constexpr (NLD == 4)
        asm volatile("s_waitcnt vmcnt(4)" ::: "memory");  // stage(t) done (wave)
      else if constexpr (NLD == 6)
        asm volatile("s_waitcnt vmcnt(6)" ::: "memory");
      else
        asm volatile("s_waitcnt vmcnt(8)" ::: "memory");
    } else {
      asm volatile("s_waitcnt vmcnt(0)" ::: "memory");    // final drain
    }
    __builtin_amdgcn_s_barrier();                 // globalize stage(t)
    compute(t & 1);
    __builtin_amdgcn_s_barrier();                 // reads done before overwrite
  }

  float* eps = (float*)smem;
  constexpr int REPS = (32 * BN) / (256 * 8);
  float bv[REPS > 0 ? REPS : 1][8];
  if (HAS_BIAS) {
#pragma unroll
    for (int rep = 0; rep < REPS; rep++) {
      const int col = (BN == 128) ? ((tid & 15) * 8) : ((tid & 7) * 8);
      *(float4*)(bv[rep])     = *(const float4*)(bias + n0 + col);
      *(float4*)(bv[rep] + 4) = *(const float4*)(bias + n0 + col + 4);
    }
  }
#pragma unroll
  for (int i = 0; i < MI; i++) {
    __syncthreads();
#pragma unroll
    for (int j = 0; j < NJ; j++)
#pragma unroll
      for (int r = 0; r < 4; r++)
        eps[(wm * 16 + quad * 4 + r) * EW + wn * WN + j * 16 + m16] =
            acc[i][j][r];
    __syncthreads();
#pragma unroll
    for (int rep = 0; rep < REPS; rep++) {
      const int lr  = (BN == 128) ? (rep * 16 + (tid >> 4)) : (tid >> 3);
      const int col = (BN == 128) ? ((tid & 15) * 8) : ((tid & 7) * 8);
      const int rg  = m0 + (lr >> 4) * WM + i * 16 + (lr & 15);
      float v[8];
      *(float4*)(v)     = *(const float4*)(eps + lr * EW + col);
      *(float4*)(v + 4) = *(const float4*)(eps + lr * EW + col + 4);
      if (SCALE_MODE != 0) {
        float rs;
        if (SCALE_MODE == 1)      rs = rowscale[rg];
        else if (SCALE_MODE == 2) rs = rsqrtf(rowscale[rg] * (1.0f / D_) + 1e-6f);
        else {
          float s4 = rowscale[rg] + rowscale[M_ + rg] +
                     rowscale[2 * M_ + rg] + rowscale[3 * M_ + rg];
          rs = rsqrtf(s4 * (1.0f / D_) + 1e-6f);
        }
#pragma unroll
        for (int e = 0; e < 8; e++) v[e] *= rs;
      }
      if (HAS_BIAS) {
#pragma unroll
        for (int e = 0; e < 8; e++) v[e] += bv[rep][e];
      }
      if (DO_GELU) {
#pragma unroll
        for (int e = 0; e < 8; e++) v[e] = gelu_f(v[e]);
      }
      const size_t idx = (size_t)rg * N + n0 + col;
      if (RES_MODE == 1) {
        float4 r0 = *(const float4*)((const float*)resv + idx);
        float4 r1 = *(const float4*)((const float*)resv + idx + 4);
        v[0] += r0.x; v[1] += r0.y; v[2] += r0.z; v[3] += r0.w;
        v[4] += r1.x; v[5] += r1.y; v[6] += r1.z; v[7] += r1.w;
      } else if (RES_MODE == 2) {
        u16x8 rr = *(const u16x8*)((const u16*)resv + idx);
#pragma unroll
        for (int e = 0; e < 8; e++) v[e] += bf2f(rr[e]);
      }
      if (EMIT_SS) {   // per-row partial sumsq (16 threads per row), no atomics
        float ps = 0.f;
#pragma unroll
        for (int e = 0; e < 8; e++) ps += v[e] * v[e];
        ps += __shfl_xor(ps, 1, 64);
        ps += __shfl_xor(ps, 2, 64);
        ps += __shfl_xor(ps, 4, 64);
        ps += __shfl_xor(ps, 8, 64);
        if ((tid & 15) == 0) ssout[(size_t)nxp * M + rg] = ps;
      }
      if (STORE_BF16) {
        u16 o[8];
#pragma unroll
        for (int e = 0; e < 8; e++) o[e] = f2bf(v[e]);
        *(uint4*)((u16*)Cv + idx) = *(uint4*)o;
      } else {
        *(float4*)((float*)Cv + idx)     = *(float4*)(v);
        *(float4*)((float*)Cv + idx + 4) = *(float4*)(v + 4);
      }
    }
  }
}

// ---- banded attention, MFMA flash-style, full-window softmax in registers.
// K staged via global_load_lds (pre-swizzled per-lane SOURCE, linear LDS dest;
// __syncthreads' vmcnt(0) certifies). V transposed manually.
#define VP_ 216
__global__ __launch_bounds__(256) void attn_kernel(const u16* __restrict__ qkv,
                                                   u16* __restrict__ out) {
  __shared__ __align__(16) char smem[26624 + 64 * VP_ * 2];
  u16* Ks = (u16*)smem;               // [208][64] keys, swizzled (26624 B)
  u16* Vt = (u16*)(smem + 26624);     // [64][216] V transposed (27648 B)
  const int tid = threadIdx.x, lane = tid & 63, w = tid >> 6;
  const int quad = lane >> 4, m16 = lane & 15;
  const int qc = ((blockIdx.x & 7) << 2) | (blockIdx.x >> 3);  // XCD swizzle
  const int q0 = qc * 64, h = blockIdx.y, b = blockIdx.z;
  const int kstart = q0 - 64;         // 208-key staging window
  const u16* base = qkv + (size_t)b * T_ * 1536;

#pragma unroll
  for (int r6 = 0; r6 < 6; r6++) {
    int c = r6 * 256 + tid;
    int row = c >> 3;
    int j = kstart + row;
    j = j < 0 ? 0 : (j > T_ - 1 ? T_ - 1 : j);
    int srcch = ((c & 7) ^ (row & 7)) * 8;
    async16(base + (size_t)j * 1536 + 512 + h * 64 + srcch, smem + c * 16);
  }
  if (tid < 128) {
    int c = 1536 + tid;
    int row = c >> 3;
    int j = kstart + row;
    j = j < 0 ? 0 : (j > T_ - 1 ? T_ - 1 : j);
    int srcch = ((c & 7) ^ (row & 7)) * 8;
    async16(base + (size_t)j * 1536 + 512 + h * 64 + srcch, smem + c * 16);
  }
  for (int c = tid; c < 1664; c += 256) {
    int row = c >> 3, cc = (c & 7) * 8;
    int j = kstart + row;
    j = j < 0 ? 0 : (j > T_ - 1 ? T_ - 1 : j);
    uint4 u = *(const uint4*)(base + (size_t)j * 1536 + 1024 + h * 64 + cc);
    u16 tmp[8];
    *(uint4*)tmp = u;
#pragma unroll
    for (int i = 0; i < 8; i++) Vt[(cc + i) * VP_ + row] = tmp[i];
  }
  const int qw = q0 + w * 16;
  const u16* qb = base + (size_t)(qw + m16) * 1536 + h * 64 + quad * 8;
  u16x8 a0 = *(const u16x8*)qb;
  u16x8 a1 = *(const u16x8*)(qb + 32);
  __syncthreads();

  float s[10][4];
#pragma unroll
  for (int t = 0; t < 10; t++) {
    int kt = (w + t) * 16;
    int kr = kt + m16, sw = kr & 7;
    u16x8 kb0 = *(const u16x8*)(Ks + kr * 64 + ((quad ^ sw) * 8));
    u16x8 kb1 = *(const u16x8*)(Ks + kr * 64 + (((4 + quad) ^ sw) * 8));
    f32x4 acc = {0.f, 0.f, 0.f, 0.f};
    acc = mfma_bf16(a0, kb0, acc);
    acc = mfma_bf16(a1, kb1, acc);
    int jab = kstart + kt + m16;
#pragma unroll
    for (int r = 0; r < 4; r++) {
      int q = qw + quad * 4 + r;
      int d = q - jab;
      bool valid = (jab >= 0) && (jab < T_) && (d <= 64) && (d >= -64);
      s[t][r] = valid ? acc[r] * 0.125f : -1e30f;
    }
  }
  float mx[4], sm[4];
#pragma unroll
  for (int r = 0; r < 4; r++) mx[r] = -1e30f;
#pragma unroll
  for (int t = 0; t < 10; t++)
#pragma unroll
    for (int r = 0; r < 4; r++) mx[r] = fmaxf(mx[r], s[t][r]);
#pragma unroll
  for (int r = 0; r < 4; r++) {
#pragma unroll
    for (int msk = 1; msk < 16; msk <<= 1)
      mx[r] = fmaxf(mx[r], __shfl_xor(mx[r], msk, 64));
    sm[r] = 0.f;
  }
#pragma unroll
  for (int t = 0; t < 10; t++)
#pragma unroll
    for (int r = 0; r < 4; r++) {
      float e = __expf(s[t][r] - mx[r]);
      s[t][r] = e; sm[r] += e;
    }
#pragma unroll
  for (int r = 0; r < 4; r++) {
#pragma unroll
    for (int msk = 1; msk < 16; msk <<= 1) sm[r] += __shfl_xor(sm[r], msk, 64);
    sm[r] = 1.0f / sm[r];
  }
  __syncthreads();
  u16* Ps = (u16*)smem + w * 2688;       // alias Ks region: per-wave [16][168]
#pragma unroll
  for (int t = 0; t < 10; t++)
#pragma unroll
    for (int r = 0; r < 4; r++)
      Ps[(quad * 4 + r) * 168 + t * 16 + m16] = f2bf(s[t][r] * sm[r]);
  __syncthreads();

  f32x4 o[4];
#pragma unroll
  for (int dt = 0; dt < 4; dt++) o[dt] = (f32x4){0.f, 0.f, 0.f, 0.f};
#pragma unroll
  for (int c5 = 0; c5 < 5; c5++) {
    u16x8 pa = *(const u16x8*)(Ps + m16 * 168 + c5 * 32 + quad * 8);
#pragma unroll
    for (int dt = 0; dt < 4; dt++) {
      u16x8 vb = *(const u16x8*)(Vt + (dt * 16 + m16) * VP_ + w * 16 + c5 * 32 + quad * 8);
      o[dt] = mfma_bf16(pa, vb, o[dt]);
    }
  }
#pragma unroll
  for (int dt = 0; dt < 4; dt++)
#pragma unroll
    for (int r = 0; r < 4; r++)
      out[(size_t)(b * T_ + qw + quad * 4 + r) * D_ + h * HD_ + dt * 16 + m16] =
          f2bf(o[dt][r]);
}

// ---------------------------------------------------------------------------
extern "C" void kernel_launch(void* const* d_in, const int* in_sizes, int n_in,
                              void* d_out, int out_size, void* d_ws, size_t ws_size,
                              hipStream_t stream) {
  (void)in_sizes; (void)n_in; (void)out_size; (void)ws_size;
  const float* x     = (const float*)d_in[0];
  const float* n1w   = (const float*)d_in[1];
  const float* n2w   = (const float*)d_in[2];
  const float* w_qkv = (const float*)d_in[3];
  const float* w_out = (const float*)d_in[4];
  const float* b_out = (const float*)d_in[5];
  const float* w1    = (const float*)d_in[6];
  const float* b1    = (const float*)d_in[7];
  const float* w2    = (const float*)d_in[8];
  const float* b2    = (const float*)d_in[9];
  float* out = (float*)d_out;
  char* ws = (char*)d_ws;

  // workspace layout (hbuf aliases dead qkv+attno)
  u16* wqkvT  = (u16*)(ws + 0);          // [1536][512]  1.5 MB (n1w folded)
  u16* woutT  = (u16*)(ws + 1572864);    // [512][512]   0.5 MB
  u16* w1T    = (u16*)(ws + 2097152);    // [2048][512]  2 MB  (n2w folded)
  u16* w2T    = (u16*)(ws + 4194304);    // [512][2048]  2 MB
  float* inv  = (float*)(ws + 6291456);  // [8192] f32 inv-rms of x
  float* sums4= (float*)(ws + 6324224);  // [4][8192] f32 partial sumsq of x1
  u16* qkv    = (u16*)(ws + 14680064);   // [8192][1536] 24 MB
  u16* attno  = (u16*)(ws + 39845888);   // [8192][512]  8 MB
  u16* x1     = (u16*)(ws + 48234496);   // [8192][512]  8 MB bf16
  u16* xbf    = (u16*)(ws + 56623104);   // [8192][512]  8 MB bf16 (raw x)
  u16* hbuf   = qkv;                     // [8192][2048] 32 MB (over qkv+attno)

  // fused: weight transposes (+norm-w fold) + x->bf16 + inv-rms
  prep_kernel<<<5120, 256, 0, stream>>>(
      w_qkv, wqkvT, w_out, woutT, w1, w1T, w2, w2T, x, n1w, n2w, inv, xbf);

  // qkv = (x @ [n1w*wqkv]) * inv[row]
  // 64x64 tile: 32KB LDS -> 5 blocks/CU (20 waves) for latency hiding.
  gemm_kernel<64, 64, false, 0, false, true, 1, false>
      <<<dim3(24 * 128), 256, 0, stream>>>(
      xbf, wqkvT, (void*)qkv, nullptr, nullptr, inv, nullptr, M_, 3 * D_, D_);
  attn_kernel<<<dim3(32, 8, 4), 256, 0, stream>>>(qkv, attno);
  // x1 = attno @ w_out + b_out + xbf ; emit per-row partial sumsq -> sums4
  gemm_kernel<64, 128, true, 2, false, true, 0, true>
      <<<dim3(4 * 128), 256, 0, stream>>>(
      attno, woutT, (void*)x1, b_out, xbf, nullptr, sums4, M_, D_, D_);
  // hbuf = gelu( (x1 @ [n2w*w1]) * rsqrt(sum4(sums4)/512+eps) + b1 )
  // 64x128 tile: 48KB LDS -> 3 blocks/CU (was 2/CU at 128x128; 50% stall r7).
  gemm_kernel<64, 128, true, 0, true, true, 3, false>
      <<<dim3(16 * 128), 256, 0, stream>>>(
      x1, w1T, (void*)hbuf, b1, nullptr, sums4, nullptr, M_, FF_, D_);
  // out = hbuf @ w2 + b2 + x1   (f32 out, bf16 res; deep K=2048, 1/CU exact)
  gemm_kernel<128, 128, true, 2, false, false, 0, false>
      <<<dim3(4 * 64), 256, 0, stream>>>(
      hbuf, w2T, (void*)out, b2, x1, nullptr, nullptr, M_, D_, FF_);
}